// Round 7
// baseline (387.153 us; speedup 1.0000x reference)
//
#include <hip/hip_runtime.h>
#include <math.h>

#define NB 4
#define NT 2048
#define ND 1024
#define NH 16
#define NHD 64
#define N3D 3072
#define M1 8192

typedef __attribute__((ext_vector_type(8))) short bf16x8;
typedef __attribute__((ext_vector_type(4))) float f32x4;
typedef __attribute__((ext_vector_type(16))) float f32x16;
typedef __attribute__((ext_vector_type(2))) int i32x2;
typedef unsigned short u16;
typedef unsigned int u32;

#define MNEG -3.0e38f

__device__ __forceinline__ u32 bf16rn(float f) {
    u32 u = __float_as_uint(f);
    return (u + 0x7FFFu + ((u >> 16) & 1u)) >> 16;
}
__device__ __forceinline__ u32 pack2(float a, float b) {
    return bf16rn(a) | (bf16rn(b) << 16);
}
__device__ __forceinline__ u32 cvtpk(float lo, float hi) {
    u32 r;
    asm("v_cvt_pk_bf16_f32 %0, %1, %2" : "=v"(r) : "v"(lo), "v"(hi));
    return r;
}
__device__ __forceinline__ void pswap(u32& a, u32& b) {
    i32x2 r = __builtin_amdgcn_permlane32_swap((int)a, (int)b, false, false);
    a = (u32)r.x; b = (u32)r.y;
}

// ---------- per-row attended-prefix bounds (pos sorted ascending per batch) ----------
__global__ __launch_bounds__(256) void bnd_kernel(const int* __restrict__ pos, int* __restrict__ Bnd) {
    const int row = blockIdx.x * 256 + threadIdx.x;    // 0..8191
    const int b = row >> 11, i = row & 2047;
    const int target = pos[b * 2048 + i];
    int lo = 0, hi = 2048;
    #pragma unroll
    for (int it = 0; it < 12; ++it) {
        const int mid = (lo + hi) >> 1;
        if (lo < hi) { if (pos[b * 2048 + mid] <= target) lo = mid + 1; else hi = mid; }
    }
    Bnd[row] = lo;
}

// ---------- convert x fp32 -> bf16 ----------
__global__ __launch_bounds__(256) void convx_kernel(const float* __restrict__ in, u16* __restrict__ out) {
    const int idx = blockIdx.x * 256 + threadIdx.x;
    const float4 v = *reinterpret_cast<const float4*>(in + (size_t)idx * 4);
    *reinterpret_cast<uint2*>(out + (size_t)idx * 4) = make_uint2(pack2(v.x, v.y), pack2(v.z, v.w));
}

// ---------- transpose + convert: fp32 [R][C] -> bf16 [C][R] ----------
__global__ __launch_bounds__(256) void tconv_kernel(const float* __restrict__ in, u16* __restrict__ out,
                                                    int R, int C) {
    __shared__ float t[32][33];
    const int bx = blockIdx.x * 32, by = blockIdx.y * 32;
    const int x = threadIdx.x, y0 = threadIdx.y;
    #pragma unroll
    for (int yy = y0; yy < 32; yy += 8) t[yy][x] = in[(size_t)(by + yy) * C + bx + x];
    __syncthreads();
    #pragma unroll
    for (int yy = y0; yy < 32; yy += 8) out[(size_t)(bx + yy) * R + by + x] = (u16)bf16rn(t[x][yy]);
}

// ---------- bf16 MFMA GEMM core (128x128 tile, BK=32, 4 waves) ----------
// SWAPPED operands: acc = mfma(bF, aF) => C^T fragments:
//   lane (g=lane>>4, col16=lane&15), reg r: C[m0+wr*64+mm*16+col16][n0+wc*64+nn*16+g*4+r]
#define GEMM_PROLOGUE(Aptr, Btptr)                                                            \
    __shared__ __align__(16) u16 As[4096];                                                    \
    __shared__ __align__(16) u16 Bs[4096];                                                    \
    const int tid = threadIdx.x;                                                              \
    const int lane = tid & 63, wave = tid >> 6;                                               \
    const int wr = wave >> 1, wc = wave & 1;                                                  \
    const int n0 = blockIdx.x * 128, m0 = blockIdx.y * 128;                                   \
    const int c0 = tid, c1 = tid + 256;                                                      \
    const int pA0 = (c0 * 16) ^ ((((c0 * 16) >> 6) & 7) << 4);                                \
    const int pA1 = (c1 * 16) ^ ((((c1 * 16) >> 6) & 7) << 4);                                \
    const u16* gA0 = Aptr + (size_t)(m0 + (c0 >> 2)) * 1024 + (c0 & 3) * 8;                   \
    const u16* gA1 = Aptr + (size_t)(m0 + (c1 >> 2)) * 1024 + (c1 & 3) * 8;                   \
    const u16* gB0 = Btptr + (size_t)(n0 + (c0 >> 2)) * 1024 + (c0 & 3) * 8;                  \
    const u16* gB1 = Btptr + (size_t)(n0 + (c1 >> 2)) * 1024 + (c1 & 3) * 8;                  \
    int offA[4], offB[4];                                                                     \
    {                                                                                         \
        const int kb = (lane >> 4) * 16;                                                      \
        _Pragma("unroll")                                                                     \
        for (int mm = 0; mm < 4; ++mm) {                                                      \
            int row = wr * 64 + mm * 16 + (lane & 15);                                        \
            offA[mm] = (row * 64 + kb) ^ ((row & 7) << 4);                                    \
        }                                                                                     \
        _Pragma("unroll")                                                                     \
        for (int nn = 0; nn < 4; ++nn) {                                                      \
            int row = wc * 64 + nn * 16 + (lane & 15);                                        \
            offB[nn] = (row * 64 + kb) ^ ((row & 7) << 4);                                    \
        }                                                                                     \
    }                                                                                         \
    f32x4 acc[4][4];                                                                          \
    _Pragma("unroll")                                                                         \
    for (int mm = 0; mm < 4; ++mm)                                                            \
        _Pragma("unroll")                                                                     \
        for (int nn = 0; nn < 4; ++nn)                                                        \
            acc[mm][nn] = (f32x4){0.f, 0.f, 0.f, 0.f};                                        \
    uint4 va0 = *(const uint4*)gA0, va1 = *(const uint4*)gA1;                                 \
    uint4 vb0 = *(const uint4*)gB0, vb1 = *(const uint4*)gB1;                                 \
    for (int k0 = 0; k0 < 1024; k0 += 32) {                                                   \
        __syncthreads();                                                                      \
        *(uint4*)((char*)As + pA0) = va0;                                                     \
        *(uint4*)((char*)As + pA1) = va1;                                                     \
        *(uint4*)((char*)Bs + pA0) = vb0;                                                     \
        *(uint4*)((char*)Bs + pA1) = vb1;                                                     \
        __syncthreads();                                                                      \
        if (k0 + 32 < 1024) {                                                                 \
            gA0 += 32; gA1 += 32; gB0 += 32; gB1 += 32;                                       \
            va0 = *(const uint4*)gA0; va1 = *(const uint4*)gA1;                               \
            vb0 = *(const uint4*)gB0; vb1 = *(const uint4*)gB1;                               \
        }                                                                                     \
        bf16x8 aF[4], bF[4];                                                                  \
        _Pragma("unroll")                                                                     \
        for (int mm = 0; mm < 4; ++mm) aF[mm] = *(const bf16x8*)((const char*)As + offA[mm]); \
        _Pragma("unroll")                                                                     \
        for (int nn = 0; nn < 4; ++nn) bF[nn] = *(const bf16x8*)((const char*)Bs + offB[nn]); \
        _Pragma("unroll")                                                                     \
        for (int mm = 0; mm < 4; ++mm)                                                        \
            _Pragma("unroll")                                                                 \
            for (int nn = 0; nn < 4; ++nn)                                                    \
                acc[mm][nn] = __builtin_amdgcn_mfma_f32_16x16x32_bf16(bF[nn], aF[mm],         \
                                                                      acc[mm][nn], 0, 0, 0); \
    }

// qkv GEMM with LDS-repack epilogue -> coalesced 1KB stores.
// Q (pre-scaled) [bh][t][d], K [bh][t][d], V TRANSPOSED [bh][d][t]
__global__ __launch_bounds__(256) void gemm_qkv_kernel(
    const u16* __restrict__ A, const u16* __restrict__ Bt,
    u16* __restrict__ Qo, u16* __restrict__ Ko, u16* __restrict__ Vo)
{
    GEMM_PROLOGUE(A, Bt)
    const int col16 = lane & 15, g4 = (lane >> 4) << 2;
    const int nb0 = n0 + wc * 64;            // 64-aligned => exactly one (s,h)
    const int tb0 = m0 + wr * 64;
    const int s  = nb0 >> 10;
    const int hh = (nb0 >> 6) & 15;
    const int t0g = tb0 & 2047;
    const int bh = ((tb0 >> 11) << 4) + hh;
    const float sc = (s == 0) ? 0.18033688011112042f : 1.0f;   // 0.125*log2(e) for Q

    __syncthreads();
    u16* lds = (wave & 1) ? Bs : As;         // 8KB per wave
    for (int round = 0; round < 2; ++round) {
        if ((wave >> 1) == round) {
            if (s < 2) {
                // write [t][d] (rows of 128B), XOR-swizzled
                #pragma unroll
                for (int mm = 0; mm < 4; ++mm) {
                    const int tl = mm * 16 + col16;
                    #pragma unroll
                    for (int nn = 0; nn < 4; ++nn) {
                        uint2 w = make_uint2(pack2(acc[mm][nn][0] * sc, acc[mm][nn][1] * sc),
                                             pack2(acc[mm][nn][2] * sc, acc[mm][nn][3] * sc));
                        const int off = (tl * 128 + (nn * 16 + g4) * 2) ^ ((tl & 7) << 4);
                        *reinterpret_cast<uint2*>((char*)lds + off) = w;
                    }
                }
                u16* dst = (s == 0) ? Qo : Ko;
                #pragma unroll
                for (int it = 0; it < 8; ++it) {
                    const int row = it * 8 + (lane >> 3);
                    const int off = (row * 128 + (lane & 7) * 16) ^ ((row & 7) << 4);
                    uint4 v = *reinterpret_cast<const uint4*>((const char*)lds + off);
                    *reinterpret_cast<uint4*>(&dst[((size_t)bh * 2048 + t0g + row) * 64 + (lane & 7) * 8]) = v;
                }
            } else {
                // V: write transposed [d][t] into LDS (scalar b16), read rows of d
                #pragma unroll
                for (int mm = 0; mm < 4; ++mm) {
                    const int tl = mm * 16 + col16;
                    #pragma unroll
                    for (int nn = 0; nn < 4; ++nn) {
                        #pragma unroll
                        for (int r = 0; r < 4; ++r) {
                            const int dl = nn * 16 + g4 + r;
                            const int off = (dl * 128 + tl * 2) ^ ((dl & 7) << 4);
                            *reinterpret_cast<u16*>((char*)lds + off) = (u16)bf16rn(acc[mm][nn][r]);
                        }
                    }
                }
                #pragma unroll
                for (int it = 0; it < 8; ++it) {
                    const int row = it * 8 + (lane >> 3);   // d_loc
                    const int off = (row * 128 + (lane & 7) * 16) ^ ((row & 7) << 4);
                    uint4 v = *reinterpret_cast<const uint4*>((const char*)lds + off);
                    *reinterpret_cast<uint4*>(&Vo[((size_t)bh * 64 + row) * 2048 + t0g + (lane & 7) * 8]) = v;
                }
            }
        }
        __syncthreads();
    }
}

// out GEMM with LDS-repack epilogue (fp32, two 32-row passes per wave)
__global__ __launch_bounds__(256) void gemm_out_kernel(
    const u16* __restrict__ A, const u16* __restrict__ Bt, float* __restrict__ C)
{
    GEMM_PROLOGUE(A, Bt)
    const int col16 = lane & 15, g4 = (lane >> 4) << 2;
    __syncthreads();
    char* lds = (char*)((wave & 1) ? Bs : As);     // 8KB = 32 rows x 64 f32
    for (int round = 0; round < 2; ++round) {
        if ((wave >> 1) == round) {
            #pragma unroll
            for (int p = 0; p < 2; ++p) {
                #pragma unroll
                for (int mmh = 0; mmh < 2; ++mmh) {
                    const int mm = p * 2 + mmh;
                    const int rl = mmh * 16 + col16;               // 0..31
                    #pragma unroll
                    for (int nn = 0; nn < 4; ++nn) {
                        const int off = (rl * 256 + (nn * 16 + g4) * 4) ^ ((rl & 7) << 4);
                        *reinterpret_cast<f32x4*>(lds + off) = acc[mm][nn];
                    }
                }
                #pragma unroll
                for (int it = 0; it < 8; ++it) {
                    const int row = it * 4 + (lane >> 4);          // 0..31
                    const int off = (row * 256 + col16 * 16) ^ ((row & 7) << 4);
                    float4 v = *reinterpret_cast<const float4*>((const char*)lds + off);
                    const int mg = m0 + wr * 64 + p * 32 + row;
                    *reinterpret_cast<float4*>(&C[(size_t)mg * 1024 + n0 + wc * 64 + col16 * 4]) = v;
                }
            }
        }
        __syncthreads();
    }
}

// ---------- MFMA flash attention, split-K chunks + partials ----------
// grid 8192 x 64 thr: (bh, qi, chunk c). Wave owns 32 q rows; key range split
// into 2 balanced chunks; partial (m,l,O-bf16) per slot. Fragment math
// identical to verified round-5/6 kernel. LPT within XCD chunk.
__global__ __launch_bounds__(64) void attn6_kernel(
    const u16* __restrict__ Q, const u16* __restrict__ K, const u16* __restrict__ Vt,
    const int* __restrict__ Bnd, u32* __restrict__ Pout)
{
    const int bid = blockIdx.x;
    const int x = bid & 7, wgl = bid >> 3;        // 8 XCDs x 1024
    const int bh = x * 8 + (wgl >> 7);
    const int w2 = wgl & 127;
    const int qi = 63 - (w2 >> 1);                // longest prefixes first
    const int c  = w2 & 1;
    const int b = bh >> 4;
    const int lane = threadIdx.x;
    const int col = lane & 31, hi = lane >> 5, hi4 = 4 * hi;
    const int i0 = qi * 32;

    const int bnd = Bnd[b * 2048 + i0 + col];
    int bmax = bnd, bmin = bnd;
    #pragma unroll
    for (int s = 1; s < 32; s <<= 1) {
        bmax = max(bmax, __shfl_xor(bmax, s));
        bmin = min(bmin, __shfl_xor(bmin, s));
    }
    const int ntiles = (bmax + 31) >> 5;
    const int halfk  = ((ntiles + 1) >> 1) << 5;
    const int kLo = c ? halfk : 0;
    const int kHi = c ? bmax : min(halfk, bmax);

    const size_t kvrow = (size_t)bh * 2048;
    const size_t vrow  = (size_t)bh * 64;

    bf16x8 qf[4];
    #pragma unroll
    for (int ds = 0; ds < 4; ++ds)
        qf[ds] = *(const bf16x8*)&Q[(kvrow + i0 + col) * 64 + ds * 16 + hi * 8];

    float mrun = MNEG, lrun = 0.f;
    f32x16 oT0, oT1;
    #pragma unroll
    for (int i = 0; i < 16; ++i) { oT0[i] = 0.f; oT1[i] = 0.f; }

    for (int j0 = kLo; j0 < kHi; j0 += 32) {
        bf16x8 kf[4], vfa[2], vfb[2];
        #pragma unroll
        for (int ds = 0; ds < 4; ++ds)
            kf[ds] = *(const bf16x8*)&K[(kvrow + j0 + col) * 64 + ds * 16 + hi * 8];
        #pragma unroll
        for (int kh = 0; kh < 2; ++kh) {
            vfa[kh] = *(const bf16x8*)&Vt[(vrow + col) * 2048 + j0 + kh * 16 + hi * 8];
            vfb[kh] = *(const bf16x8*)&Vt[(vrow + 32 + col) * 2048 + j0 + kh * 16 + hi * 8];
        }

        f32x16 st;
        #pragma unroll
        for (int i = 0; i < 16; ++i) st[i] = 0.f;
        #pragma unroll
        for (int ds = 0; ds < 4; ++ds)
            st = __builtin_amdgcn_mfma_f32_32x32x16_bf16(kf[ds], qf[ds], st, 0, 0, 0);

        if (j0 + 32 > bmin) {
            #pragma unroll
            for (int r = 0; r < 16; ++r) {
                const int kg = j0 + ((r & 3) + 8 * (r >> 2)) + hi4;
                if (kg >= bnd) st[r] = -INFINITY;
            }
        }

        float rm = st[0];
        #pragma unroll
        for (int r = 1; r < 16; ++r) rm = fmaxf(rm, st[r]);
        rm = fmaxf(rm, __shfl_xor(rm, 32));
        if (__any(rm > mrun)) {
            const float mnew = fmaxf(mrun, rm);
            const float factor = __builtin_amdgcn_exp2f(mrun - mnew);
            mrun = mnew;
            lrun *= factor;
            #pragma unroll
            for (int i = 0; i < 16; ++i) { oT0[i] *= factor; oT1[i] *= factor; }
        }
        float psum = 0.f;
        #pragma unroll
        for (int r = 0; r < 16; ++r) {
            const float p = __builtin_amdgcn_exp2f(st[r] - mrun);
            st[r] = p;
            psum += p;
        }
        psum += __shfl_xor(psum, 32);
        lrun += psum;

        u32 W[8];
        #pragma unroll
        for (int r = 0; r < 8; ++r) W[r] = cvtpk(st[2 * r], st[2 * r + 1]);
        u32 a0 = W[0], b0 = W[2]; pswap(a0, b0);
        u32 a1 = W[1], b1 = W[3]; pswap(a1, b1);
        u32 a2 = W[4], b2 = W[6]; pswap(a2, b2);
        u32 a3 = W[5], b3 = W[7]; pswap(a3, b3);
        union { u32 w[4]; bf16x8 v; } p0, p1;
        p0.w[0] = a0; p0.w[1] = a1; p0.w[2] = b0; p0.w[3] = b1;
        p1.w[0] = a2; p1.w[1] = a3; p1.w[2] = b2; p1.w[3] = b3;

        oT0 = __builtin_amdgcn_mfma_f32_32x32x16_bf16(vfa[0], p0.v, oT0, 0, 0, 0);
        oT0 = __builtin_amdgcn_mfma_f32_32x32x16_bf16(vfa[1], p1.v, oT0, 0, 0, 0);
        oT1 = __builtin_amdgcn_mfma_f32_32x32x16_bf16(vfb[0], p0.v, oT1, 0, 0, 0);
        oT1 = __builtin_amdgcn_mfma_f32_32x32x16_bf16(vfb[1], p1.v, oT1, 0, 0, 0);
    }

    // write partial slot: 16x O-pair (bf16) + m + l, lane-major coalesced
    const int slot = ((bh << 6) + qi) * 2 + c;
    u32* P = Pout + (size_t)slot * 1152 + lane;
    #pragma unroll
    for (int w = 0; w < 8; ++w) P[w * 64] = cvtpk(oT0[2 * w], oT0[2 * w + 1]);
    #pragma unroll
    for (int w = 0; w < 8; ++w) P[(8 + w) * 64] = cvtpk(oT1[2 * w], oT1[2 * w + 1]);
    P[16 * 64] = __float_as_uint(mrun);
    P[17 * 64] = __float_as_uint(lrun);
}

// ---------- combine partials -> AO ----------
__global__ __launch_bounds__(64) void attn_combine_kernel(
    const u32* __restrict__ P, u16* __restrict__ AO)
{
    const int t = blockIdx.x;                 // bh*64 + qi
    const int bh = t >> 6, qi = t & 63;
    const int b = bh >> 4, h = bh & 15;
    const int lane = threadIdx.x;
    const int col = lane & 31, hi4 = 4 * (lane >> 5);
    const u32* A  = P + (size_t)(t * 2) * 1152 + lane;
    const u32* Bp = A + 1152;
    const float mA = __uint_as_float(A[16 * 64]),  lA = __uint_as_float(A[17 * 64]);
    const float mB = __uint_as_float(Bp[16 * 64]), lB = __uint_as_float(Bp[17 * 64]);
    const float mN = fmaxf(mA, mB);
    const float fA = __builtin_amdgcn_exp2f(mA - mN);
    const float fB = __builtin_amdgcn_exp2f(mB - mN);
    const float inv = 1.f / (lA * fA + lB * fB);
    u16* dst = &AO[((size_t)(b * 2048 + qi * 32 + col)) * 1024 + h * 64];
    #pragma unroll
    for (int w = 0; w < 16; ++w) {
        const u32 wa = A[w * 64], wb = Bp[w * 64];
        const float a0 = __uint_as_float(wa << 16), a1 = __uint_as_float(wa & 0xFFFF0000u);
        const float b0 = __uint_as_float(wb << 16), b1 = __uint_as_float(wb & 0xFFFF0000u);
        const float o0 = (a0 * fA + b0 * fB) * inv;
        const float o1 = (a1 * fA + b1 * fB) * inv;
        const int wl = w & 7;
        const int dloc = 8 * (wl >> 1) + 2 * (wl & 1) + hi4 + ((w >> 3) << 5);
        *reinterpret_cast<u32*>(&dst[dloc]) = cvtpk(o0, o1);
    }
}

extern "C" void kernel_launch(void* const* d_in, const int* in_sizes, int n_in,
                              void* d_out, int out_size, void* d_ws, size_t ws_size,
                              hipStream_t stream) {
    (void)in_sizes; (void)n_in; (void)out_size; (void)ws_size;
    const float* x    = (const float*)d_in[0];
    const int*   pos  = (const int*)d_in[1];
    const float* Wqkv = (const float*)d_in[2];
    const float* Wout = (const float*)d_in[3];
    float* out = (float*)d_out;

    char* ws = (char*)d_ws;
    u16* xb    = (u16*)(ws);                    // 16 MB (aliased as AO)
    u16* WqkvT = (u16*)(ws + 16777216);         // 6 MB
    u16* WoutT = (u16*)(ws + 23068672);         // 2 MB
    u16* Qb    = (u16*)(ws + 25165824);         // 16 MB bf16 [bh][t][d], pre-scaled
    u16* Kb    = (u16*)(ws + 41943040);         // 16 MB bf16 [bh][t][d]
    u16* Vtb   = (u16*)(ws + 58720256);         // 16 MB bf16 [bh][d][t]
    u32* Part  = (u32*)(ws + 75497472);         // 36 MB partials (8192 x 4608B)
    int* Bnd   = (int*)(ws + 113246208);        // 32 KB per-row bounds
    u16* AO    = xb;

    bnd_kernel<<<dim3(M1 / 256), dim3(256), 0, stream>>>(pos, Bnd);
    convx_kernel<<<dim3(M1 * ND / (256 * 4)), dim3(256), 0, stream>>>(x, xb);
    tconv_kernel<<<dim3(N3D / 32, ND / 32), dim3(32, 8), 0, stream>>>(Wqkv, WqkvT, ND, N3D);
    tconv_kernel<<<dim3(ND / 32, ND / 32), dim3(32, 8), 0, stream>>>(Wout, WoutT, ND, ND);
    gemm_qkv_kernel<<<dim3(N3D / 128, M1 / 128), dim3(256), 0, stream>>>(xb, WqkvT, Qb, Kb, Vtb);
    attn6_kernel<<<dim3(8192), dim3(64), 0, stream>>>(Qb, Kb, Vtb, Bnd, Part);
    attn_combine_kernel<<<dim3(4096), dim3(64), 0, stream>>>(Part, AO);
    gemm_out_kernel<<<dim3(ND / 128, M1 / 128), dim3(256), 0, stream>>>(AO, WoutT, out);
}

// Round 8
// 381.823 us; speedup vs baseline: 1.0140x; 1.0140x over previous
//
#include <hip/hip_runtime.h>
#include <math.h>

#define NB 4
#define NT 2048
#define ND 1024
#define NH 16
#define NHD 64
#define N3D 3072
#define M1 8192

typedef __attribute__((ext_vector_type(8))) short bf16x8;
typedef __attribute__((ext_vector_type(4))) float f32x4;
typedef __attribute__((ext_vector_type(16))) float f32x16;
typedef __attribute__((ext_vector_type(2))) int i32x2;
typedef unsigned short u16;
typedef unsigned int u32;

#define MNEG -3.0e38f

__device__ __forceinline__ u32 bf16rn(float f) {
    u32 u = __float_as_uint(f);
    return (u + 0x7FFFu + ((u >> 16) & 1u)) >> 16;
}
__device__ __forceinline__ u32 pack2(float a, float b) {
    return bf16rn(a) | (bf16rn(b) << 16);
}
__device__ __forceinline__ u32 cvtpk(float lo, float hi) {
    u32 r;
    asm("v_cvt_pk_bf16_f32 %0, %1, %2" : "=v"(r) : "v"(lo), "v"(hi));
    return r;
}
__device__ __forceinline__ void pswap(u32& a, u32& b) {
    i32x2 r = __builtin_amdgcn_permlane32_swap((int)a, (int)b, false, false);
    a = (u32)r.x; b = (u32)r.y;
}

// ---------- per-row attended-prefix bounds ----------
__global__ __launch_bounds__(256) void bnd_kernel(const int* __restrict__ pos, int* __restrict__ Bnd) {
    const int row = blockIdx.x * 256 + threadIdx.x;
    const int b = row >> 11, i = row & 2047;
    const int target = pos[b * 2048 + i];
    int lo = 0, hi = 2048;
    #pragma unroll
    for (int it = 0; it < 12; ++it) {
        const int mid = (lo + hi) >> 1;
        if (lo < hi) { if (pos[b * 2048 + mid] <= target) lo = mid + 1; else hi = mid; }
    }
    Bnd[row] = lo;
}

// ---------- convert x fp32 -> bf16 ----------
__global__ __launch_bounds__(256) void convx_kernel(const float* __restrict__ in, u16* __restrict__ out) {
    const int idx = blockIdx.x * 256 + threadIdx.x;
    const float4 v = *reinterpret_cast<const float4*>(in + (size_t)idx * 4);
    *reinterpret_cast<uint2*>(out + (size_t)idx * 4) = make_uint2(pack2(v.x, v.y), pack2(v.z, v.w));
}

// ---------- transpose + convert: fp32 [R][C] -> bf16 [C][R] ----------
__global__ __launch_bounds__(256) void tconv_kernel(const float* __restrict__ in, u16* __restrict__ out,
                                                    int R, int C) {
    __shared__ float t[32][33];
    const int bx = blockIdx.x * 32, by = blockIdx.y * 32;
    const int x = threadIdx.x, y0 = threadIdx.y;
    #pragma unroll
    for (int yy = y0; yy < 32; yy += 8) t[yy][x] = in[(size_t)(by + yy) * C + bx + x];
    __syncthreads();
    #pragma unroll
    for (int yy = y0; yy < 32; yy += 8) out[(size_t)(bx + yy) * R + by + x] = (u16)bf16rn(t[x][yy]);
}

// ---------- V transpose: bf16 [bh][t][d] -> [bh][d][t] ----------
__global__ __launch_bounds__(256) void vtrans_kernel(const u16* __restrict__ in, u16* __restrict__ out) {
    __shared__ u16 t[32][34];
    const int dx = blockIdx.x * 32, ty0 = blockIdx.y * 32, bh = blockIdx.z;
    const int x = threadIdx.x, y0 = threadIdx.y;
    const u16* src = in + ((size_t)bh * 2048 + ty0) * 64 + dx;
    #pragma unroll
    for (int yy = y0; yy < 32; yy += 8) t[yy][x] = src[yy * 64 + x];
    __syncthreads();
    u16* dst = out + ((size_t)bh * 64 + dx) * 2048 + ty0;
    #pragma unroll
    for (int yy = y0; yy < 32; yy += 8) dst[(size_t)yy * 2048 + x] = t[x][yy];
}

// ---------- bf16 MFMA GEMM core (128x128 tile, BK=32, 4 waves) ----------
// Round-2-proven: acc = mfma(aF, bF) => C[m0+wr*64+mm*16+(lane>>4)*4+r][n0+wc*64+nn*16+(lane&15)]
#define GEMM_PROLOGUE(Aptr, Btptr)                                                            \
    __shared__ __align__(16) u16 As[4096];                                                    \
    __shared__ __align__(16) u16 Bs[4096];                                                    \
    const int tid = threadIdx.x;                                                              \
    const int lane = tid & 63, wave = tid >> 6;                                               \
    const int wr = wave >> 1, wc = wave & 1;                                                  \
    const int n0 = blockIdx.x * 128, m0 = blockIdx.y * 128;                                   \
    const int c0 = tid, c1 = tid + 256;                                                       \
    const int pA0 = (c0 * 16) ^ ((((c0 * 16) >> 6) & 7) << 4);                                \
    const int pA1 = (c1 * 16) ^ ((((c1 * 16) >> 6) & 7) << 4);                                \
    const u16* gA0 = Aptr + (size_t)(m0 + (c0 >> 2)) * 1024 + (c0 & 3) * 8;                   \
    const u16* gA1 = Aptr + (size_t)(m0 + (c1 >> 2)) * 1024 + (c1 & 3) * 8;                   \
    const u16* gB0 = Btptr + (size_t)(n0 + (c0 >> 2)) * 1024 + (c0 & 3) * 8;                  \
    const u16* gB1 = Btptr + (size_t)(n0 + (c1 >> 2)) * 1024 + (c1 & 3) * 8;                  \
    int offA[4], offB[4];                                                                     \
    {                                                                                         \
        const int kb = (lane >> 4) * 16;                                                      \
        _Pragma("unroll")                                                                     \
        for (int mm = 0; mm < 4; ++mm) {                                                      \
            int row = wr * 64 + mm * 16 + (lane & 15);                                        \
            offA[mm] = (row * 64 + kb) ^ ((row & 7) << 4);                                    \
        }                                                                                     \
        _Pragma("unroll")                                                                     \
        for (int nn = 0; nn < 4; ++nn) {                                                      \
            int row = wc * 64 + nn * 16 + (lane & 15);                                        \
            offB[nn] = (row * 64 + kb) ^ ((row & 7) << 4);                                    \
        }                                                                                     \
    }                                                                                         \
    f32x4 acc[4][4];                                                                          \
    _Pragma("unroll")                                                                         \
    for (int mm = 0; mm < 4; ++mm)                                                            \
        _Pragma("unroll")                                                                     \
        for (int nn = 0; nn < 4; ++nn)                                                       \
            acc[mm][nn] = (f32x4){0.f, 0.f, 0.f, 0.f};                                        \
    uint4 va0 = *(const uint4*)gA0, va1 = *(const uint4*)gA1;                                 \
    uint4 vb0 = *(const uint4*)gB0, vb1 = *(const uint4*)gB1;                                 \
    for (int k0 = 0; k0 < 1024; k0 += 32) {                                                   \
        __syncthreads();                                                                      \
        *(uint4*)((char*)As + pA0) = va0;                                                     \
        *(uint4*)((char*)As + pA1) = va1;                                                     \
        *(uint4*)((char*)Bs + pA0) = vb0;                                                     \
        *(uint4*)((char*)Bs + pA1) = vb1;                                                     \
        __syncthreads();                                                                      \
        if (k0 + 32 < 1024) {                                                                 \
            gA0 += 32; gA1 += 32; gB0 += 32; gB1 += 32;                                       \
            va0 = *(const uint4*)gA0; va1 = *(const uint4*)gA1;                               \
            vb0 = *(const uint4*)gB0; vb1 = *(const uint4*)gB1;                               \
        }                                                                                     \
        bf16x8 aF[4], bF[4];                                                                  \
        _Pragma("unroll")                                                                     \
        for (int mm = 0; mm < 4; ++mm) aF[mm] = *(const bf16x8*)((const char*)As + offA[mm]); \
        _Pragma("unroll")                                                                     \
        for (int nn = 0; nn < 4; ++nn) bF[nn] = *(const bf16x8*)((const char*)Bs + offB[nn]); \
        _Pragma("unroll")                                                                     \
        for (int mm = 0; mm < 4; ++mm)                                                        \
            _Pragma("unroll")                                                                 \
            for (int nn = 0; nn < 4; ++nn)                                                    \
                acc[mm][nn] = __builtin_amdgcn_mfma_f32_16x16x32_bf16(aF[mm], bF[nn],         \
                                                                      acc[mm][nn], 0, 0, 0); \
    }

// qkv GEMM: bf16 Q (pre-scaled), K, V all [bh][t][d]; round-2-style scalar epilogue
__global__ __launch_bounds__(256) void gemm_qkv_kernel(
    const u16* __restrict__ A, const u16* __restrict__ Bt,
    u16* __restrict__ Qo, u16* __restrict__ Ko, u16* __restrict__ Vo)
{
    GEMM_PROLOGUE(A, Bt)
    const int nbase = n0 + wc * 64;          // 64-aligned: one (s,h) per wave
    const int s  = nbase >> 10;
    const int hh = (nbase >> 6) & 15;
    u16* dst = (s == 0) ? Qo : (s == 1) ? Ko : Vo;
    const float sc = (s == 0) ? 0.18033688011112042f : 1.0f;   // 0.125*log2(e) for Q
    #pragma unroll
    for (int nn = 0; nn < 4; ++nn) {
        const int hd = nn * 16 + (lane & 15);
        #pragma unroll
        for (int mm = 0; mm < 4; ++mm) {
            const int rbase = m0 + wr * 64 + mm * 16 + ((lane >> 4) << 2);
            const int bq = rbase >> 11, t0 = rbase & 2047;
            const size_t base = ((size_t)((bq << 4) + hh) * 2048 + t0) * 64 + hd;
            #pragma unroll
            for (int r = 0; r < 4; ++r)
                dst[base + (size_t)r * 64] = (u16)bf16rn(acc[mm][nn][r] * sc);
        }
    }
}

// out GEMM: fp32 C row-major, round-2-style scalar epilogue
__global__ __launch_bounds__(256) void gemm_out_kernel(
    const u16* __restrict__ A, const u16* __restrict__ Bt, float* __restrict__ C)
{
    GEMM_PROLOGUE(A, Bt)
    #pragma unroll
    for (int nn = 0; nn < 4; ++nn) {
        const int n_abs = n0 + wc * 64 + nn * 16 + (lane & 15);
        #pragma unroll
        for (int mm = 0; mm < 4; ++mm) {
            const int rbase = m0 + wr * 64 + mm * 16 + ((lane >> 4) << 2);
            #pragma unroll
            for (int r = 0; r < 4; ++r)
                C[(size_t)(rbase + r) * 1024 + n_abs] = acc[mm][nn][r];
        }
    }
}

// ---------- MFMA flash attention: 4 independent wave-units / 256-thr block ----------
// grid 2048. Unit = (bh, qi, chunk): wave owns 32 q rows, split-K=2, partials out.
// Verified 32x32x16 math (S^T = mfma(K,Q); P^T via cvt_pk+permlane32_swap;
// O^T = mfma(V^T,P^T)). No LDS/barriers. K prefetched one tile ahead.
__global__ __launch_bounds__(256, 4) void attn7_kernel(
    const u16* __restrict__ Q, const u16* __restrict__ K, const u16* __restrict__ Vt,
    const int* __restrict__ Bnd, u32* __restrict__ Pout)
{
    const int tid = threadIdx.x, lane = tid & 63, wave = tid >> 6;
    const int bid = blockIdx.x;
    const int x = bid & 7, bl = bid >> 3;         // XCD, block-in-XCD (256 each)
    const int bh = x * 8 + (bl >> 5);             // 8 heads per XCD
    const int u  = (bl & 31) * 4 + wave;          // 0..127 unit in head
    const int qi = 63 - (u >> 1);                 // longest prefixes first
    const int c  = u & 1;
    const int b = bh >> 4;
    const int col = lane & 31, hi = lane >> 5, hi4 = 4 * hi;
    const int i0 = qi * 32;

    const int bnd = Bnd[b * 2048 + i0 + col];
    int bmax = bnd, bmin = bnd;
    #pragma unroll
    for (int s = 1; s < 32; s <<= 1) {
        bmax = max(bmax, __shfl_xor(bmax, s));
        bmin = min(bmin, __shfl_xor(bmin, s));
    }
    const int ntiles = (bmax + 31) >> 5;
    const int halfk  = ((ntiles + 1) >> 1) << 5;
    const int kLo = c ? halfk : 0;
    const int kHi = c ? bmax : min(halfk, bmax);

    const size_t kvrow = (size_t)bh * 2048;
    const size_t vrow  = (size_t)bh * 64;

    bf16x8 qf[4];
    #pragma unroll
    for (int ds = 0; ds < 4; ++ds)
        qf[ds] = *(const bf16x8*)&Q[(kvrow + i0 + col) * 64 + ds * 16 + hi * 8];

    float mrun = MNEG, lrun = 0.f;
    f32x16 oT0, oT1;
    #pragma unroll
    for (int i = 0; i < 16; ++i) { oT0[i] = 0.f; oT1[i] = 0.f; }

    // preload K fragments for first tile (kLo < 2048 always: safe)
    bf16x8 kf[4];
    #pragma unroll
    for (int ds = 0; ds < 4; ++ds)
        kf[ds] = *(const bf16x8*)&K[(kvrow + kLo + col) * 64 + ds * 16 + hi * 8];

    for (int j0 = kLo; j0 < kHi; j0 += 32) {
        // V^T loads for this tile: issue now, consumed after softmax
        bf16x8 vfa[2], vfb[2];
        #pragma unroll
        for (int kh = 0; kh < 2; ++kh) {
            vfa[kh] = *(const bf16x8*)&Vt[(vrow + col) * 2048 + j0 + kh * 16 + hi * 8];
            vfb[kh] = *(const bf16x8*)&Vt[(vrow + 32 + col) * 2048 + j0 + kh * 16 + hi * 8];
        }

        // S^T = K · Q^T over d=64
        f32x16 st;
        #pragma unroll
        for (int i = 0; i < 16; ++i) st[i] = 0.f;
        __builtin_amdgcn_s_setprio(1);
        #pragma unroll
        for (int ds = 0; ds < 4; ++ds)
            st = __builtin_amdgcn_mfma_f32_32x32x16_bf16(kf[ds], qf[ds], st, 0, 0, 0);
        __builtin_amdgcn_s_setprio(0);

        // prefetch next-tile K fragments
        const int jn = (j0 + 32 < kHi) ? j0 + 32 : j0;
        bf16x8 kf2[4];
        #pragma unroll
        for (int ds = 0; ds < 4; ++ds)
            kf2[ds] = *(const bf16x8*)&K[(kvrow + jn + col) * 64 + ds * 16 + hi * 8];

        // mask: k_global >= bnd(q)
        if (j0 + 32 > bmin) {
            #pragma unroll
            for (int r = 0; r < 16; ++r) {
                const int kg = j0 + ((r & 3) + 8 * (r >> 2)) + hi4;
                if (kg >= bnd) st[r] = -INFINITY;
            }
        }

        // online softmax (exp2 domain), exact rescale-skip
        float rm = st[0];
        #pragma unroll
        for (int r = 1; r < 16; ++r) rm = fmaxf(rm, st[r]);
        rm = fmaxf(rm, __shfl_xor(rm, 32));
        if (__any(rm > mrun)) {
            const float mnew = fmaxf(mrun, rm);
            const float factor = __builtin_amdgcn_exp2f(mrun - mnew);
            mrun = mnew;
            lrun *= factor;
            #pragma unroll
            for (int i = 0; i < 16; ++i) { oT0[i] *= factor; oT1[i] *= factor; }
        }
        float psum = 0.f;
        #pragma unroll
        for (int r = 0; r < 16; ++r) {
            const float p = __builtin_amdgcn_exp2f(st[r] - mrun);
            st[r] = p;
            psum += p;
        }
        psum += __shfl_xor(psum, 32);
        lrun += psum;

        // pack P^T, build B-frags via permlane32_swap
        u32 W[8];
        #pragma unroll
        for (int r = 0; r < 8; ++r) W[r] = cvtpk(st[2 * r], st[2 * r + 1]);
        u32 a0 = W[0], b0 = W[2]; pswap(a0, b0);
        u32 a1 = W[1], b1 = W[3]; pswap(a1, b1);
        u32 a2 = W[4], b2 = W[6]; pswap(a2, b2);
        u32 a3 = W[5], b3 = W[7]; pswap(a3, b3);
        union { u32 w[4]; bf16x8 v; } p0, p1;
        p0.w[0] = a0; p0.w[1] = a1; p0.w[2] = b0; p0.w[3] = b1;
        p1.w[0] = a2; p1.w[1] = a3; p1.w[2] = b2; p1.w[3] = b3;

        // PV: O^T += V^T · P^T
        __builtin_amdgcn_s_setprio(1);
        oT0 = __builtin_amdgcn_mfma_f32_32x32x16_bf16(vfa[0], p0.v, oT0, 0, 0, 0);
        oT0 = __builtin_amdgcn_mfma_f32_32x32x16_bf16(vfa[1], p1.v, oT0, 0, 0, 0);
        oT1 = __builtin_amdgcn_mfma_f32_32x32x16_bf16(vfb[0], p0.v, oT1, 0, 0, 0);
        oT1 = __builtin_amdgcn_mfma_f32_32x32x16_bf16(vfb[1], p1.v, oT1, 0, 0, 0);
        __builtin_amdgcn_s_setprio(0);

        #pragma unroll
        for (int ds = 0; ds < 4; ++ds) kf[ds] = kf2[ds];
    }

    // partial slot: 16x O-pair (bf16) + m + l, lane-major coalesced
    const int slot = ((bh << 6) + qi) * 2 + c;
    u32* P = Pout + (size_t)slot * 1152 + lane;
    #pragma unroll
    for (int w = 0; w < 8; ++w) P[w * 64] = cvtpk(oT0[2 * w], oT0[2 * w + 1]);
    #pragma unroll
    for (int w = 0; w < 8; ++w) P[(8 + w) * 64] = cvtpk(oT1[2 * w], oT1[2 * w + 1]);
    P[16 * 64] = __float_as_uint(mrun);
    P[17 * 64] = __float_as_uint(lrun);
}

// ---------- combine partials -> AO (4 units per 256-thr block) ----------
__global__ __launch_bounds__(256) void attn_combine_kernel(
    const u32* __restrict__ P, u16* __restrict__ AO)
{
    const int tid = threadIdx.x, lane = tid & 63, wave = tid >> 6;
    const int t = blockIdx.x * 4 + wave;          // bh*64 + qi
    const int bh = t >> 6, qi = t & 63;
    const int b = bh >> 4, h = bh & 15;
    const int col = lane & 31, hi4 = 4 * (lane >> 5);
    const u32* A  = P + (size_t)(t * 2) * 1152 + lane;
    const u32* Bp = A + 1152;
    const float mA = __uint_as_float(A[16 * 64]),  lA = __uint_as_float(A[17 * 64]);
    const float mB = __uint_as_float(Bp[16 * 64]), lB = __uint_as_float(Bp[17 * 64]);
    const float mN = fmaxf(mA, mB);
    const float fA = __builtin_amdgcn_exp2f(mA - mN);
    const float fB = __builtin_amdgcn_exp2f(mB - mN);
    const float inv = 1.f / (lA * fA + lB * fB);
    u16* dst = &AO[((size_t)(b * 2048 + qi * 32 + col)) * 1024 + h * 64];
    #pragma unroll
    for (int w = 0; w < 16; ++w) {
        const u32 wa = A[w * 64], wb = Bp[w * 64];
        const float a0 = __uint_as_float(wa << 16), a1 = __uint_as_float(wa & 0xFFFF0000u);
        const float b0 = __uint_as_float(wb << 16), b1 = __uint_as_float(wb & 0xFFFF0000u);
        const float o0 = (a0 * fA + b0 * fB) * inv;
        const float o1 = (a1 * fA + b1 * fB) * inv;
        const int wl = w & 7;
        const int dloc = 8 * (wl >> 1) + 2 * (wl & 1) + hi4 + ((w >> 3) << 5);
        *reinterpret_cast<u32*>(&dst[dloc]) = cvtpk(o0, o1);
    }
}

extern "C" void kernel_launch(void* const* d_in, const int* in_sizes, int n_in,
                              void* d_out, int out_size, void* d_ws, size_t ws_size,
                              hipStream_t stream) {
    (void)in_sizes; (void)n_in; (void)out_size; (void)ws_size;
    const float* x    = (const float*)d_in[0];
    const int*   pos  = (const int*)d_in[1];
    const float* Wqkv = (const float*)d_in[2];
    const float* Wout = (const float*)d_in[3];
    float* out = (float*)d_out;

    char* ws = (char*)d_ws;
    u16* xb    = (u16*)(ws);                    // 16 MB (aliased as AO after gemm1)
    u16* WqkvT = (u16*)(ws + 16777216);         // 6 MB
    u16* WoutT = (u16*)(ws + 23068672);         // 2 MB
    u16* Qb    = (u16*)(ws + 25165824);         // 16 MB bf16 [bh][t][d], pre-scaled
    u16* Kb    = (u16*)(ws + 41943040);         // 16 MB bf16 [bh][t][d]
    u16* Vtb   = (u16*)(ws + 58720256);         // 16 MB bf16 [bh][d][t]
    u16* Vb    = (u16*)(ws + 75497472);         // 16 MB bf16 [bh][t][d] (dead after vtrans)
    u32* Part  = (u32*)(ws + 75497472);         // 37.75 MB partials (aliases Vb - OK, Vb dead)
    int* Bnd   = (int*)(ws + 113246208);        // 32 KB per-row bounds
    u16* AO    = xb;

    bnd_kernel<<<dim3(M1 / 256), dim3(256), 0, stream>>>(pos, Bnd);
    convx_kernel<<<dim3(M1 * ND / (256 * 4)), dim3(256), 0, stream>>>(x, xb);
    tconv_kernel<<<dim3(N3D / 32, ND / 32), dim3(32, 8), 0, stream>>>(Wqkv, WqkvT, ND, N3D);
    tconv_kernel<<<dim3(ND / 32, ND / 32), dim3(32, 8), 0, stream>>>(Wout, WoutT, ND, ND);
    gemm_qkv_kernel<<<dim3(N3D / 128, M1 / 128), dim3(256), 0, stream>>>(xb, WqkvT, Qb, Kb, Vb);
    vtrans_kernel<<<dim3(2, 64, 64), dim3(32, 8), 0, stream>>>(Vb, Vtb);
    attn7_kernel<<<dim3(2048), dim3(256), 0, stream>>>(Qb, Kb, Vtb, Bnd, Part);
    attn_combine_kernel<<<dim3(1024), dim3(256), 0, stream>>>(Part, AO);
    gemm_out_kernel<<<dim3(ND / 128, M1 / 128), dim3(256), 0, stream>>>(AO, WoutT, out);
}